// Round 4
// baseline (50.488 us; speedup 1.0000x reference)
//
#include <hip/hip_runtime.h>
#include <math.h>

// Problem sizes (fixed by reference setup_inputs)
#define NP      (128 * 196)   // 25088 patches
#define PATCH   768           // elements per patch
#define ND      128           // contrastive N
#define DD      256           // contrastive D
#define TEMP_INV 10.0f        // 1 / 0.1
#define COS_EPS_F 1e-8f

#define NPW     4                 // patches per wave, ALL loads issued upfront
#define NWAVE_R (NP / NPW)        // 6272 recon waves
#define NB_R    (NWAVE_R / 4)     // 1568 recon blocks (4 waves each)
#define NB_C    32                // contrastive blocks (4 rows each -> 128 rows)

__device__ __forceinline__ float wave_sum(float v) {
#pragma unroll
    for (int o = 32; o; o >>= 1) v += __shfl_xor(v, o);
    return v;
}
__device__ __forceinline__ float wave_max(float v) {
#pragma unroll
    for (int o = 32; o; o >>= 1) v = fmaxf(v, __shfl_xor(v, o));
    return v;
}
__device__ __forceinline__ float dot4(float4 a, float4 b) {
    return a.x * b.x + a.y * b.y + a.z * b.z + a.w * b.w;
}

// ws layout (floats):
//   [0          .. NWAVE_R)     per-wave weighted-loss partial
//   [NWAVE_R    .. 2*NWAVE_R)   per-wave mask-sum partial
//   [2*NWAVE_R  .. +128)        per-row contrastive contribution (lse_i - S_ii/T)
__global__ __launch_bounds__(256, 1) void partials_kernel(
    const float* __restrict__ preds,   // student_prob [128,256]
    const float* __restrict__ tgts,    // teacher_prob [128,256]
    const float* __restrict__ rt,      // reconstruct_target [B,L,P]
    const float* __restrict__ rp,      // reconstruct_pred   [B,L,P]
    const float* __restrict__ mask,    // [B,L]
    float* __restrict__ ws)
{
    const int tid  = threadIdx.x;
    const int w    = tid >> 6;
    const int lane = tid & 63;
    const int blk  = blockIdx.x;

    if (blk < NB_R) {
        // ---- reconstruction: 4 patches/wave, ALL 24 loads in flight ----
        const int gw = blk * 4 + w;          // 0..6271
        const int p0 = gw * NPW;
        const float4* t4 = (const float4*)(rt + (size_t)p0 * PATCH) + lane;
        const float4* q4 = (const float4*)(rp + (size_t)p0 * PATCH) + lane;

        float4 T[NPW][3], Q[NPW][3];
#pragma unroll
        for (int p = 0; p < NPW; ++p)
#pragma unroll
            for (int q = 0; q < 3; ++q) {
                T[p][q] = t4[p * (PATCH / 4) + q * 64];
                Q[p][q] = q4[p * (PATCH / 4) + q * 64];
            }
        const float4 mv = *(const float4*)(mask + p0);   // wave-uniform broadcast

        // 5 linear sums per patch (per-lane partials)
        float s[NPW], ss[NPW], sp[NPW], spp[NPW], spt[NPW];
#pragma unroll
        for (int p = 0; p < NPW; ++p) {
            s[p] = ss[p] = sp[p] = spp[p] = spt[p] = 0.f;
#pragma unroll
            for (int q = 0; q < 3; ++q) {
                float4 t = T[p][q], pv = Q[p][q];
                s[p]   += t.x + t.y + t.z + t.w;
                ss[p]  += dot4(t, t);
                sp[p]  += pv.x + pv.y + pv.z + pv.w;
                spp[p] += dot4(pv, pv);
                spt[p] += dot4(pv, t);
            }
        }
        // ONE butterfly phase over all 20 values: 6-step chain, 20-wide ILP
#pragma unroll
        for (int o = 32; o; o >>= 1) {
#pragma unroll
            for (int p = 0; p < NPW; ++p) {
                s[p]   += __shfl_xor(s[p], o);
                ss[p]  += __shfl_xor(ss[p], o);
                sp[p]  += __shfl_xor(sp[p], o);
                spp[p] += __shfl_xor(spp[p], o);
                spt[p] += __shfl_xor(spt[p], o);
            }
        }
        const float mk[NPW] = { mv.x, mv.y, mv.z, mv.w };
        float acc_l = 0.f;
#pragma unroll
        for (int p = 0; p < NPW; ++p) {
            const float mean = s[p] * (1.0f / PATCH);
            const float cvar = ss[p] - s[p] * mean;              // Σ(t-mean)²
            const float var  = cvar * (1.0f / (PATCH - 1));
            const float rstd = 1.0f / sqrtf(var + 1e-6f);
            // Σ(q - (t-mean)·rstd)² = spp - 2·rstd·(spt - mean·sp) + rstd²·cvar
            const float lsum = spp[p] - 2.f * rstd * (spt[p] - mean * sp[p])
                             + rstd * rstd * cvar;
            acc_l += lsum * (1.0f / PATCH) * mk[p];
        }
        if (lane == 0) {
            ws[gw]           = acc_l;
            ws[NWAVE_R + gw] = mv.x + mv.y + mv.z + mv.w;
        }
    } else {
        // ---------------- contrastive per-row contributions ----------------
        __shared__ float4 pn4s[4][DD / 4];
        const int cb = blk - NB_R;       // 0..31
        const int i  = cb * 4 + w;       // row 0..127
        const float4* pg = (const float4*)preds;
        const float4* tg = (const float4*)tgts;

        // stage normalized pred row i into LDS (wave-local)
        float4 v = pg[(size_t)i * (DD / 4) + lane];
        float ssp = wave_sum(dot4(v, v));
        float invp = 1.0f / fmaxf(sqrtf(ssp), COS_EPS_F);
        pn4s[w][lane] = make_float4(v.x * invp, v.y * invp, v.z * invp, v.w * invp);
        __syncthreads();

        // lane j reads full teacher row j: accumulate dot AND row norm inline
        const int j1 = lane, j2 = lane + 64;
        float d1 = 0.f, d2 = 0.f, n1 = 0.f, n2 = 0.f;
#pragma unroll 8
        for (int k = 0; k < DD / 4; ++k) {
            float4 c = pn4s[w][k];                 // LDS broadcast
            float4 a = tg[j1 * (DD / 4) + k];
            float4 b = tg[j2 * (DD / 4) + k];
            d1 += dot4(c, a);  n1 += dot4(a, a);
            d2 += dot4(c, b);  n2 += dot4(b, b);
        }
        const float s1 = d1 * (1.0f / fmaxf(sqrtf(n1), COS_EPS_F)) * TEMP_INV;
        const float s2 = d2 * (1.0f / fmaxf(sqrtf(n2), COS_EPS_F)) * TEMP_INV;
        float m = wave_max(fmaxf(s1, s2));
        float sum = wave_sum(expf(s1 - m) + expf(s2 - m));
        const float lse = m + logf(sum);
        const float pos = (i < 64) ? __shfl(s1, i) : __shfl(s2, i - 64);
        if (lane == 0) ws[2 * NWAVE_R + i] = lse - pos;
    }
}

__global__ __launch_bounds__(256) void finalize_kernel(
    const float* __restrict__ ws, float* __restrict__ out)
{
    __shared__ float s_red[12];
    const int tid = threadIdx.x, w = tid >> 6, lane = tid & 63;
    float a = 0.f, b = 0.f, c = 0.f;
    for (int i = tid; i < NWAVE_R; i += 256) {
        a += ws[i];
        b += ws[NWAVE_R + i];
    }
    if (tid < ND) c = ws[2 * NWAVE_R + tid];
    a = wave_sum(a); b = wave_sum(b); c = wave_sum(c);
    if (lane == 0) { s_red[w] = a; s_red[4 + w] = b; s_red[8 + w] = c; }
    __syncthreads();
    if (tid == 0) {
        float la = 0.f, lb = 0.f, lc = 0.f;
#pragma unroll
        for (int k = 0; k < 4; ++k) {
            la += s_red[k]; lb += s_red[4 + k]; lc += s_red[8 + k];
        }
        const float recon = la / lb;
        const float contr = lc / (float)ND;
        out[0] = recon;
        out[1] = contr;
        out[2] = recon + contr;
    }
}

extern "C" void kernel_launch(void* const* d_in, const int* in_sizes, int n_in,
                              void* d_out, int out_size, void* d_ws, size_t ws_size,
                              hipStream_t stream) {
    const float* student = (const float*)d_in[0];
    const float* teacher = (const float*)d_in[1];
    const float* rt      = (const float*)d_in[2];
    const float* rp      = (const float*)d_in[3];
    const float* mask    = (const float*)d_in[4];
    float* ws  = (float*)d_ws;
    float* out = (float*)d_out;

    hipLaunchKernelGGL(partials_kernel, dim3(NB_R + NB_C), dim3(256), 0, stream,
                       student, teacher, rt, rp, mask, ws);
    hipLaunchKernelGGL(finalize_kernel, dim3(1), dim3(256), 0, stream, ws, out);
}

// Round 6
// 49.233 us; speedup vs baseline: 1.0255x; 1.0255x over previous
//
#include <hip/hip_runtime.h>
#include <math.h>

// Problem sizes (fixed by reference setup_inputs)
#define NP      (128 * 196)   // 25088 patches
#define PATCH   768           // elements per patch
#define ND      128           // contrastive N
#define DD      256           // contrastive D
#define TEMP_INV 10.0f        // 1 / 0.1
#define COS_EPS_F 1e-8f

#define NPW     4                 // patches per wave, ALL loads issued upfront
#define NWAVE_R (NP / NPW)        // 6272 recon waves
#define NB_R    (NWAVE_R / 4)     // 1568 recon blocks (4 waves each)
#define NB_C    32                // contrastive blocks (4 rows each -> 128 rows)

typedef float nf4 __attribute__((ext_vector_type(4)));  // native vec4 for builtins

__device__ __forceinline__ float wave_sum(float v) {
#pragma unroll
    for (int o = 32; o; o >>= 1) v += __shfl_xor(v, o);
    return v;
}
__device__ __forceinline__ float wave_max(float v) {
#pragma unroll
    for (int o = 32; o; o >>= 1) v = fmaxf(v, __shfl_xor(v, o));
    return v;
}
__device__ __forceinline__ float dot4(float4 a, float4 b) {
    return a.x * b.x + a.y * b.y + a.z * b.z + a.w * b.w;
}
__device__ __forceinline__ float ndot(nf4 a, nf4 b) {
    return a.x * b.x + a.y * b.y + a.z * b.z + a.w * b.w;
}
__device__ __forceinline__ float nsum(nf4 a) {
    return a.x + a.y + a.z + a.w;
}

// ws layout (floats):
//   [0          .. NWAVE_R)     per-wave weighted-loss partial
//   [NWAVE_R    .. 2*NWAVE_R)   per-wave mask-sum partial
//   [2*NWAVE_R  .. +128)        per-row contrastive contribution (lse_i - S_ii/T)
__global__ __launch_bounds__(256, 2) void partials_kernel(
    const float* __restrict__ preds,   // student_prob [128,256]
    const float* __restrict__ tgts,    // teacher_prob [128,256]
    const float* __restrict__ rt,      // reconstruct_target [B,L,P]
    const float* __restrict__ rp,      // reconstruct_pred   [B,L,P]
    const float* __restrict__ mask,    // [B,L]
    float* __restrict__ ws)
{
    const int tid  = threadIdx.x;
    const int w    = tid >> 6;
    const int lane = tid & 63;
    const int blk  = blockIdx.x;

    if (blk < NB_R) {
        // ---- reconstruction: 4 patches/wave, ALL 24 loads forced in flight ----
        const int gw = blk * 4 + w;          // 0..6271
        const int p0 = gw * NPW;
        const nf4* t4 = (const nf4*)(rt + (size_t)p0 * PATCH) + lane;
        const nf4* q4 = (const nf4*)(rp + (size_t)p0 * PATCH) + lane;

        const float4 mv = *(const float4*)(mask + p0);   // wave-uniform broadcast

        nf4 T[NPW][3], Q[NPW][3];
#pragma unroll
        for (int p = 0; p < NPW; ++p)
#pragma unroll
            for (int q = 0; q < 3; ++q) {
                T[p][q] = __builtin_nontemporal_load(&t4[p * (PATCH / 4) + q * 64]);
                Q[p][q] = __builtin_nontemporal_load(&q4[p * (PATCH / 4) + q * 64]);
            }
        // Hard scheduling fence: nothing moves across. All 24 load results
        // must be live here -> compiler cannot sink/serialize the loads.
        __builtin_amdgcn_sched_barrier(0);

        // 5 linear sums per patch (per-lane partials)
        float s[NPW], ss[NPW], sp[NPW], spp[NPW], spt[NPW];
#pragma unroll
        for (int p = 0; p < NPW; ++p) {
            s[p] = ss[p] = sp[p] = spp[p] = spt[p] = 0.f;
#pragma unroll
            for (int q = 0; q < 3; ++q) {
                nf4 t = T[p][q], pv = Q[p][q];
                s[p]   += nsum(t);
                ss[p]  += ndot(t, t);
                sp[p]  += nsum(pv);
                spp[p] += ndot(pv, pv);
                spt[p] += ndot(pv, t);
            }
        }
        // ONE butterfly phase over all 20 values: 6-step chain, 20-wide ILP
#pragma unroll
        for (int o = 32; o; o >>= 1) {
#pragma unroll
            for (int p = 0; p < NPW; ++p) {
                s[p]   += __shfl_xor(s[p], o);
                ss[p]  += __shfl_xor(ss[p], o);
                sp[p]  += __shfl_xor(sp[p], o);
                spp[p] += __shfl_xor(spp[p], o);
                spt[p] += __shfl_xor(spt[p], o);
            }
        }
        const float mk[NPW] = { mv.x, mv.y, mv.z, mv.w };
        float acc_l = 0.f;
#pragma unroll
        for (int p = 0; p < NPW; ++p) {
            const float mean = s[p] * (1.0f / PATCH);
            const float cvar = ss[p] - s[p] * mean;              // Σ(t-mean)²
            const float var  = cvar * (1.0f / (PATCH - 1));
            const float rstd = 1.0f / sqrtf(var + 1e-6f);
            // Σ(q - (t-mean)·rstd)² = spp - 2·rstd·(spt - mean·sp) + rstd²·cvar
            const float lsum = spp[p] - 2.f * rstd * (spt[p] - mean * sp[p])
                             + rstd * rstd * cvar;
            acc_l += lsum * (1.0f / PATCH) * mk[p];
        }
        if (lane == 0) {
            ws[gw]           = acc_l;
            ws[NWAVE_R + gw] = mv.x + mv.y + mv.z + mv.w;
        }
    } else {
        // ---------------- contrastive per-row contributions ----------------
        __shared__ float4 pn4s[4][DD / 4];
        const int cb = blk - NB_R;       // 0..31
        const int i  = cb * 4 + w;       // row 0..127
        const float4* pg = (const float4*)preds;
        const float4* tg = (const float4*)tgts;

        // stage normalized pred row i into LDS (wave-local)
        float4 v = pg[(size_t)i * (DD / 4) + lane];
        float ssp = wave_sum(dot4(v, v));
        float invp = 1.0f / fmaxf(sqrtf(ssp), COS_EPS_F);
        pn4s[w][lane] = make_float4(v.x * invp, v.y * invp, v.z * invp, v.w * invp);
        __syncthreads();

        // lane j reads full teacher row j: accumulate dot AND row norm inline
        const int j1 = lane, j2 = lane + 64;
        float d1 = 0.f, d2 = 0.f, n1 = 0.f, n2 = 0.f;
#pragma unroll 8
        for (int k = 0; k < DD / 4; ++k) {
            float4 c = pn4s[w][k];                 // LDS broadcast
            float4 a = tg[j1 * (DD / 4) + k];
            float4 b = tg[j2 * (DD / 4) + k];
            d1 += dot4(c, a);  n1 += dot4(a, a);
            d2 += dot4(c, b);  n2 += dot4(b, b);
        }
        const float s1 = d1 * (1.0f / fmaxf(sqrtf(n1), COS_EPS_F)) * TEMP_INV;
        const float s2 = d2 * (1.0f / fmaxf(sqrtf(n2), COS_EPS_F)) * TEMP_INV;
        float m = wave_max(fmaxf(s1, s2));
        float sum = wave_sum(expf(s1 - m) + expf(s2 - m));
        const float lse = m + logf(sum);
        const float pos = (i < 64) ? __shfl(s1, i) : __shfl(s2, i - 64);
        if (lane == 0) ws[2 * NWAVE_R + i] = lse - pos;
    }
}

__global__ __launch_bounds__(256) void finalize_kernel(
    const float* __restrict__ ws, float* __restrict__ out)
{
    __shared__ float s_red[12];
    const int tid = threadIdx.x, w = tid >> 6, lane = tid & 63;
    float a = 0.f, b = 0.f, c = 0.f;
    for (int i = tid; i < NWAVE_R; i += 256) {
        a += ws[i];
        b += ws[NWAVE_R + i];
    }
    if (tid < ND) c = ws[2 * NWAVE_R + tid];
    a = wave_sum(a); b = wave_sum(b); c = wave_sum(c);
    if (lane == 0) { s_red[w] = a; s_red[4 + w] = b; s_red[8 + w] = c; }
    __syncthreads();
    if (tid == 0) {
        float la = 0.f, lb = 0.f, lc = 0.f;
#pragma unroll
        for (int k = 0; k < 4; ++k) {
            la += s_red[k]; lb += s_red[4 + k]; lc += s_red[8 + k];
        }
        const float recon = la / lb;
        const float contr = lc / (float)ND;
        out[0] = recon;
        out[1] = contr;
        out[2] = recon + contr;
    }
}

extern "C" void kernel_launch(void* const* d_in, const int* in_sizes, int n_in,
                              void* d_out, int out_size, void* d_ws, size_t ws_size,
                              hipStream_t stream) {
    const float* student = (const float*)d_in[0];
    const float* teacher = (const float*)d_in[1];
    const float* rt      = (const float*)d_in[2];
    const float* rp      = (const float*)d_in[3];
    const float* mask    = (const float*)d_in[4];
    float* ws  = (float*)d_ws;
    float* out = (float*)d_out;

    hipLaunchKernelGGL(partials_kernel, dim3(NB_R + NB_C), dim3(256), 0, stream,
                       student, teacher, rt, rp, mask, ws);
    hipLaunchKernelGGL(finalize_kernel, dim3(1), dim3(256), 0, stream, ws, out);
}

// Round 7
// 45.317 us; speedup vs baseline: 1.1141x; 1.0864x over previous
//
#include <hip/hip_runtime.h>
#include <math.h>

// Problem sizes (fixed by reference setup_inputs)
#define NP      (128 * 196)   // 25088 patches
#define PATCH   768           // elements per patch
#define ND      128           // contrastive N
#define DD      256           // contrastive D
#define TEMP_INV 10.0f        // 1 / 0.1
#define COS_EPS_F 1e-8f

#define NPW     4                 // patches per wave, ALL 24 loads forced in flight
#define NWAVE_R (NP / NPW)        // 6272 recon waves
#define NB_R    (NWAVE_R / 4)     // 1568 recon blocks (4 waves each)
#define NB_C    32                // contrastive blocks (4 rows each -> 128 rows)

typedef float nf4 __attribute__((ext_vector_type(4)));  // native vec4

__device__ __forceinline__ float wave_sum(float v) {
#pragma unroll
    for (int o = 32; o; o >>= 1) v += __shfl_xor(v, o);
    return v;
}
__device__ __forceinline__ float wave_max(float v) {
#pragma unroll
    for (int o = 32; o; o >>= 1) v = fmaxf(v, __shfl_xor(v, o));
    return v;
}
__device__ __forceinline__ float dot4(float4 a, float4 b) {
    return a.x * b.x + a.y * b.y + a.z * b.z + a.w * b.w;
}
__device__ __forceinline__ float ndot(nf4 a, nf4 b) {
    return a.x * b.x + a.y * b.y + a.z * b.z + a.w * b.w;
}
__device__ __forceinline__ float nsum(nf4 a) {
    return a.x + a.y + a.z + a.w;
}

// ws layout (floats):
//   [0          .. NWAVE_R)     per-wave weighted-loss partial
//   [NWAVE_R    .. 2*NWAVE_R)   per-wave mask-sum partial
//   [2*NWAVE_R  .. +128)        per-row contrastive contribution (lse_i - S_ii/T)
__global__ void partials_kernel(
    const float* __restrict__ preds,   // student_prob [128,256]
    const float* __restrict__ tgts,    // teacher_prob [128,256]
    const float* __restrict__ rt,      // reconstruct_target [B,L,P]
    const float* __restrict__ rp,      // reconstruct_pred   [B,L,P]
    const float* __restrict__ mask,    // [B,L]
    float* __restrict__ ws)
{
    const int tid  = threadIdx.x;
    const int w    = tid >> 6;
    const int lane = tid & 63;
    const int blk  = blockIdx.x;

    if (blk >= NB_C) {
        // ---- reconstruction: 4 patches/wave, 24 loads forced in flight ----
        const int gw = (blk - NB_C) * 4 + w;     // 0..6271
        const int p0 = gw * NPW;
        const nf4* t4 = (const nf4*)(rt + (size_t)p0 * PATCH) + lane;
        const nf4* q4 = (const nf4*)(rp + (size_t)p0 * PATCH) + lane;

        const float4 mv = *(const float4*)(mask + p0);   // wave-uniform broadcast

        const nf4* a0 = t4;        const nf4* a1 = t4 + 192;
        const nf4* a2 = t4 + 384;  const nf4* a3 = t4 + 576;
        const nf4* b0 = q4;        const nf4* b1 = q4 + 192;
        const nf4* b2 = q4 + 384;  const nf4* b3 = q4 + 576;

        nf4 t00, t01, t02, t10, t11, t12, t20, t21, t22, t30, t31, t32;
        nf4 u00, u01, u02, u10, u11, u12, u20, u21, u22, u30, u31, u32;

        // One atomic asm blob: 24 loads issued back-to-back, all 24 results
        // early-clobber-live until the trailing waitcnt. RA cannot serialize.
        asm volatile(
            "global_load_dwordx4 %0,  %[a0], off\n\t"
            "global_load_dwordx4 %1,  %[a0], off offset:1024\n\t"
            "global_load_dwordx4 %2,  %[a0], off offset:2048\n\t"
            "global_load_dwordx4 %3,  %[a1], off\n\t"
            "global_load_dwordx4 %4,  %[a1], off offset:1024\n\t"
            "global_load_dwordx4 %5,  %[a1], off offset:2048\n\t"
            "global_load_dwordx4 %6,  %[a2], off\n\t"
            "global_load_dwordx4 %7,  %[a2], off offset:1024\n\t"
            "global_load_dwordx4 %8,  %[a2], off offset:2048\n\t"
            "global_load_dwordx4 %9,  %[a3], off\n\t"
            "global_load_dwordx4 %10, %[a3], off offset:1024\n\t"
            "global_load_dwordx4 %11, %[a3], off offset:2048\n\t"
            "global_load_dwordx4 %12, %[b0], off\n\t"
            "global_load_dwordx4 %13, %[b0], off offset:1024\n\t"
            "global_load_dwordx4 %14, %[b0], off offset:2048\n\t"
            "global_load_dwordx4 %15, %[b1], off\n\t"
            "global_load_dwordx4 %16, %[b1], off offset:1024\n\t"
            "global_load_dwordx4 %17, %[b1], off offset:2048\n\t"
            "global_load_dwordx4 %18, %[b2], off\n\t"
            "global_load_dwordx4 %19, %[b2], off offset:1024\n\t"
            "global_load_dwordx4 %20, %[b2], off offset:2048\n\t"
            "global_load_dwordx4 %21, %[b3], off\n\t"
            "global_load_dwordx4 %22, %[b3], off offset:1024\n\t"
            "global_load_dwordx4 %23, %[b3], off offset:2048\n\t"
            "s_waitcnt vmcnt(0)"
            : "=&v"(t00), "=&v"(t01), "=&v"(t02),
              "=&v"(t10), "=&v"(t11), "=&v"(t12),
              "=&v"(t20), "=&v"(t21), "=&v"(t22),
              "=&v"(t30), "=&v"(t31), "=&v"(t32),
              "=&v"(u00), "=&v"(u01), "=&v"(u02),
              "=&v"(u10), "=&v"(u11), "=&v"(u12),
              "=&v"(u20), "=&v"(u21), "=&v"(u22),
              "=&v"(u30), "=&v"(u31), "=&v"(u32)
            : [a0]"v"(a0), [a1]"v"(a1), [a2]"v"(a2), [a3]"v"(a3),
              [b0]"v"(b0), [b1]"v"(b1), [b2]"v"(b2), [b3]"v"(b3));

        const nf4 T[NPW][3] = {{t00, t01, t02}, {t10, t11, t12},
                               {t20, t21, t22}, {t30, t31, t32}};
        const nf4 Q[NPW][3] = {{u00, u01, u02}, {u10, u11, u12},
                               {u20, u21, u22}, {u30, u31, u32}};

        // 5 linear sums per patch (per-lane partials)
        float s[NPW], ss[NPW], sp[NPW], spp[NPW], spt[NPW];
#pragma unroll
        for (int p = 0; p < NPW; ++p) {
            s[p] = ss[p] = sp[p] = spp[p] = spt[p] = 0.f;
#pragma unroll
            for (int q = 0; q < 3; ++q) {
                nf4 t = T[p][q], pv = Q[p][q];
                s[p]   += nsum(t);
                ss[p]  += ndot(t, t);
                sp[p]  += nsum(pv);
                spp[p] += ndot(pv, pv);
                spt[p] += ndot(pv, t);
            }
        }
        // ONE butterfly phase over all 20 values: 6-step chain, 20-wide ILP
#pragma unroll
        for (int o = 32; o; o >>= 1) {
#pragma unroll
            for (int p = 0; p < NPW; ++p) {
                s[p]   += __shfl_xor(s[p], o);
                ss[p]  += __shfl_xor(ss[p], o);
                sp[p]  += __shfl_xor(sp[p], o);
                spp[p] += __shfl_xor(spp[p], o);
                spt[p] += __shfl_xor(spt[p], o);
            }
        }
        const float mk[NPW] = { mv.x, mv.y, mv.z, mv.w };
        float acc_l = 0.f;
#pragma unroll
        for (int p = 0; p < NPW; ++p) {
            const float mean = s[p] * (1.0f / PATCH);
            const float cvar = ss[p] - s[p] * mean;              // Σ(t-mean)²
            const float var  = cvar * (1.0f / (PATCH - 1));
            const float rstd = 1.0f / sqrtf(var + 1e-6f);
            // Σ(q - (t-mean)·rstd)² = spp - 2·rstd·(spt - mean·sp) + rstd²·cvar
            const float lsum = spp[p] - 2.f * rstd * (spt[p] - mean * sp[p])
                             + rstd * rstd * cvar;
            acc_l += lsum * (1.0f / PATCH) * mk[p];
        }
        if (lane == 0) {
            ws[gw]           = acc_l;
            ws[NWAVE_R + gw] = mv.x + mv.y + mv.z + mv.w;
        }
    } else {
        // ---------------- contrastive per-row contributions ----------------
        __shared__ float4 pn4s[4][DD / 4];
        const int i  = blk * 4 + w;      // row 0..127
        const float4* pg = (const float4*)preds;
        const float4* tg = (const float4*)tgts;

        // stage normalized pred row i into LDS (wave-local)
        float4 v = pg[(size_t)i * (DD / 4) + lane];
        float ssp = wave_sum(dot4(v, v));
        float invp = 1.0f / fmaxf(sqrtf(ssp), COS_EPS_F);
        pn4s[w][lane] = make_float4(v.x * invp, v.y * invp, v.z * invp, v.w * invp);
        __syncthreads();

        // lane j reads full teacher row j: accumulate dot AND row norm inline
        const int j1 = lane, j2 = lane + 64;
        float d1 = 0.f, d2 = 0.f, n1 = 0.f, n2 = 0.f;
#pragma unroll 8
        for (int k = 0; k < DD / 4; ++k) {
            float4 c = pn4s[w][k];                 // LDS broadcast
            float4 a = tg[j1 * (DD / 4) + k];
            float4 b = tg[j2 * (DD / 4) + k];
            d1 += dot4(c, a);  n1 += dot4(a, a);
            d2 += dot4(c, b);  n2 += dot4(b, b);
        }
        const float s1 = d1 * (1.0f / fmaxf(sqrtf(n1), COS_EPS_F)) * TEMP_INV;
        const float s2 = d2 * (1.0f / fmaxf(sqrtf(n2), COS_EPS_F)) * TEMP_INV;
        float m = wave_max(fmaxf(s1, s2));
        float sum = wave_sum(expf(s1 - m) + expf(s2 - m));
        const float lse = m + logf(sum);
        const float pos = (i < 64) ? __shfl(s1, i) : __shfl(s2, i - 64);
        if (lane == 0) ws[2 * NWAVE_R + i] = lse - pos;
    }
}

__global__ __launch_bounds__(256) void finalize_kernel(
    const float* __restrict__ ws, float* __restrict__ out)
{
    __shared__ float s_red[12];
    const int tid = threadIdx.x, w = tid >> 6, lane = tid & 63;
    float a = 0.f, b = 0.f, c = 0.f;
    for (int i = tid; i < NWAVE_R; i += 256) {
        a += ws[i];
        b += ws[NWAVE_R + i];
    }
    if (tid < ND) c = ws[2 * NWAVE_R + tid];
    a = wave_sum(a); b = wave_sum(b); c = wave_sum(c);
    if (lane == 0) { s_red[w] = a; s_red[4 + w] = b; s_red[8 + w] = c; }
    __syncthreads();
    if (tid == 0) {
        float la = 0.f, lb = 0.f, lc = 0.f;
#pragma unroll
        for (int k = 0; k < 4; ++k) {
            la += s_red[k]; lb += s_red[4 + k]; lc += s_red[8 + k];
        }
        const float recon = la / lb;
        const float contr = lc / (float)ND;
        out[0] = recon;
        out[1] = contr;
        out[2] = recon + contr;
    }
}

extern "C" void kernel_launch(void* const* d_in, const int* in_sizes, int n_in,
                              void* d_out, int out_size, void* d_ws, size_t ws_size,
                              hipStream_t stream) {
    const float* student = (const float*)d_in[0];
    const float* teacher = (const float*)d_in[1];
    const float* rt      = (const float*)d_in[2];
    const float* rp      = (const float*)d_in[3];
    const float* mask    = (const float*)d_in[4];
    float* ws  = (float*)d_ws;
    float* out = (float*)d_out;

    hipLaunchKernelGGL(partials_kernel, dim3(NB_C + NB_R), dim3(256), 0, stream,
                       student, teacher, rt, rp, mask, ws);
    hipLaunchKernelGGL(finalize_kernel, dim3(1), dim3(256), 0, stream, ws, out);
}

// Round 8
// 39.708 us; speedup vs baseline: 1.2715x; 1.1412x over previous
//
#include <hip/hip_runtime.h>
#include <math.h>

// Problem sizes (fixed by reference setup_inputs)
#define NP      (128 * 196)   // 25088 patches
#define PATCH   768           // elements per patch
#define ND      128           // contrastive N
#define DD      256           // contrastive D
#define TEMP_INV 10.0f        // 1 / 0.1
#define COS_EPS_F 1e-8f

#define NPW     4                 // patches per wave
#define NWAVE_R (NP / NPW)        // 6272 recon waves
#define NB_R    (NWAVE_R / 4)     // 1568 recon blocks (4 waves each)
#define NB_C    32                // contrastive blocks (4 rows each -> 128 rows)

typedef float nf4 __attribute__((ext_vector_type(4)));  // native vec4 for builtins

__device__ __forceinline__ float wave_sum(float v) {
#pragma unroll
    for (int o = 32; o; o >>= 1) v += __shfl_xor(v, o);
    return v;
}
__device__ __forceinline__ float wave_max(float v) {
#pragma unroll
    for (int o = 32; o; o >>= 1) v = fmaxf(v, __shfl_xor(v, o));
    return v;
}
__device__ __forceinline__ float dot4(float4 a, float4 b) {
    return a.x * b.x + a.y * b.y + a.z * b.z + a.w * b.w;
}
__device__ __forceinline__ float ndot(nf4 a, nf4 b) {
    return a.x * b.x + a.y * b.y + a.z * b.z + a.w * b.w;
}
__device__ __forceinline__ float nsum(nf4 a) {
    return a.x + a.y + a.z + a.w;
}

// ws layout (floats):
//   [0          .. NWAVE_R)     per-wave weighted-loss partial
//   [NWAVE_R    .. 2*NWAVE_R)   per-wave mask-sum partial
//   [2*NWAVE_R  .. +128)        per-row contrastive contribution (lse_i - S_ii/T)
__global__ __launch_bounds__(256, 2) void partials_kernel(
    const float* __restrict__ preds,   // student_prob [128,256]
    const float* __restrict__ tgts,    // teacher_prob [128,256]
    const float* __restrict__ rt,      // reconstruct_target [B,L,P]
    const float* __restrict__ rp,      // reconstruct_pred   [B,L,P]
    const float* __restrict__ mask,    // [B,L]
    float* __restrict__ ws)
{
    const int tid  = threadIdx.x;
    const int w    = tid >> 6;
    const int lane = tid & 63;
    const int blk  = blockIdx.x;

    if (blk >= NB_C) {
        // ---- reconstruction: 4 patches/wave; SKIP loads where mask==0 ----
        const int gw = (blk - NB_C) * 4 + w;     // 0..6271
        const int p0 = gw * NPW;
        const nf4* t4 = (const nf4*)(rt + (size_t)p0 * PATCH) + lane;
        const nf4* q4 = (const nf4*)(rp + (size_t)p0 * PATCH) + lane;

        const float4 mv = *(const float4*)(mask + p0);   // wave-uniform broadcast
        const float mk[NPW] = { mv.x, mv.y, mv.z, mv.w };

        nf4 T[NPW][3], Q[NPW][3];
        // Guarded nontemporal loads: mask is identical across the wave, so
        // each branch is wave-uniform (no divergence). ~25% of patches have
        // mask==0 and contribute exactly 0 -> never read their 6 KB.
#pragma unroll
        for (int p = 0; p < NPW; ++p) {
            if (mk[p] != 0.f) {
#pragma unroll
                for (int q = 0; q < 3; ++q) {
                    T[p][q] = __builtin_nontemporal_load(&t4[p * (PATCH / 4) + q * 64]);
                    Q[p][q] = __builtin_nontemporal_load(&q4[p * (PATCH / 4) + q * 64]);
                }
            }
        }
        __builtin_amdgcn_sched_barrier(0);

        // 5 linear sums per patch (per-lane partials); zeros for skipped
        float s[NPW], ss[NPW], sp[NPW], spp[NPW], spt[NPW];
#pragma unroll
        for (int p = 0; p < NPW; ++p) {
            s[p] = ss[p] = sp[p] = spp[p] = spt[p] = 0.f;
            if (mk[p] != 0.f) {
#pragma unroll
                for (int q = 0; q < 3; ++q) {
                    nf4 t = T[p][q], pv = Q[p][q];
                    s[p]   += nsum(t);
                    ss[p]  += ndot(t, t);
                    sp[p]  += nsum(pv);
                    spp[p] += ndot(pv, pv);
                    spt[p] += ndot(pv, t);
                }
            }
        }
        // ONE butterfly phase over all 20 values (zeros pass through safely)
#pragma unroll
        for (int o = 32; o; o >>= 1) {
#pragma unroll
            for (int p = 0; p < NPW; ++p) {
                s[p]   += __shfl_xor(s[p], o);
                ss[p]  += __shfl_xor(ss[p], o);
                sp[p]  += __shfl_xor(sp[p], o);
                spp[p] += __shfl_xor(spp[p], o);
                spt[p] += __shfl_xor(spt[p], o);
            }
        }
        float acc_l = 0.f;
#pragma unroll
        for (int p = 0; p < NPW; ++p) {
            const float mean = s[p] * (1.0f / PATCH);
            const float cvar = ss[p] - s[p] * mean;              // Σ(t-mean)²
            const float var  = cvar * (1.0f / (PATCH - 1));
            const float rstd = 1.0f / sqrtf(var + 1e-6f);        // finite even for zeros
            // Σ(q - (t-mean)·rstd)² = spp - 2·rstd·(spt - mean·sp) + rstd²·cvar
            const float lsum = spp[p] - 2.f * rstd * (spt[p] - mean * sp[p])
                             + rstd * rstd * cvar;
            acc_l += lsum * (1.0f / PATCH) * mk[p];
        }
        if (lane == 0) {
            ws[gw]           = acc_l;
            ws[NWAVE_R + gw] = mk[0] + mk[1] + mk[2] + mk[3];
        }
    } else {
        // ---------------- contrastive per-row contributions ----------------
        __shared__ float4 pn4s[4][DD / 4];
        const int i  = blk * 4 + w;      // row 0..127
        const float4* pg = (const float4*)preds;
        const float4* tg = (const float4*)tgts;

        // stage normalized pred row i into LDS (wave-local)
        float4 v = pg[(size_t)i * (DD / 4) + lane];
        float ssp = wave_sum(dot4(v, v));
        float invp = 1.0f / fmaxf(sqrtf(ssp), COS_EPS_F);
        pn4s[w][lane] = make_float4(v.x * invp, v.y * invp, v.z * invp, v.w * invp);
        __syncthreads();

        // lane j reads full teacher row j: accumulate dot AND row norm inline
        const int j1 = lane, j2 = lane + 64;
        float d1 = 0.f, d2 = 0.f, n1 = 0.f, n2 = 0.f;
#pragma unroll 8
        for (int k = 0; k < DD / 4; ++k) {
            float4 c = pn4s[w][k];                 // LDS broadcast
            float4 a = tg[j1 * (DD / 4) + k];
            float4 b = tg[j2 * (DD / 4) + k];
            d1 += dot4(c, a);  n1 += dot4(a, a);
            d2 += dot4(c, b);  n2 += dot4(b, b);
        }
        const float s1 = d1 * (1.0f / fmaxf(sqrtf(n1), COS_EPS_F)) * TEMP_INV;
        const float s2 = d2 * (1.0f / fmaxf(sqrtf(n2), COS_EPS_F)) * TEMP_INV;
        float m = wave_max(fmaxf(s1, s2));
        float sum = wave_sum(expf(s1 - m) + expf(s2 - m));
        const float lse = m + logf(sum);
        const float pos = (i < 64) ? __shfl(s1, i) : __shfl(s2, i - 64);
        if (lane == 0) ws[2 * NWAVE_R + i] = lse - pos;
    }
}

__global__ __launch_bounds__(256) void finalize_kernel(
    const float* __restrict__ ws, float* __restrict__ out)
{
    __shared__ float s_red[12];
    const int tid = threadIdx.x, w = tid >> 6, lane = tid & 63;
    float a = 0.f, b = 0.f, c = 0.f;
    for (int i = tid; i < NWAVE_R; i += 256) {
        a += ws[i];
        b += ws[NWAVE_R + i];
    }
    if (tid < ND) c = ws[2 * NWAVE_R + tid];
    a = wave_sum(a); b = wave_sum(b); c = wave_sum(c);
    if (lane == 0) { s_red[w] = a; s_red[4 + w] = b; s_red[8 + w] = c; }
    __syncthreads();
    if (tid == 0) {
        float la = 0.f, lb = 0.f, lc = 0.f;
#pragma unroll
        for (int k = 0; k < 4; ++k) {
            la += s_red[k]; lb += s_red[4 + k]; lc += s_red[8 + k];
        }
        const float recon = la / lb;
        const float contr = lc / (float)ND;
        out[0] = recon;
        out[1] = contr;
        out[2] = recon + contr;
    }
}

extern "C" void kernel_launch(void* const* d_in, const int* in_sizes, int n_in,
                              void* d_out, int out_size, void* d_ws, size_t ws_size,
                              hipStream_t stream) {
    const float* student = (const float*)d_in[0];
    const float* teacher = (const float*)d_in[1];
    const float* rt      = (const float*)d_in[2];
    const float* rp      = (const float*)d_in[3];
    const float* mask    = (const float*)d_in[4];
    float* ws  = (float*)d_ws;
    float* out = (float*)d_out;

    hipLaunchKernelGGL(partials_kernel, dim3(NB_C + NB_R), dim3(256), 0, stream,
                       student, teacher, rt, rp, mask, ws);
    hipLaunchKernelGGL(finalize_kernel, dim3(1), dim3(256), 0, stream, ws, out);
}